// Round 17
// baseline (97.141 us; speedup 1.0000x reference)
//
#include <hip/hip_runtime.h>

#define N_SRC 8192
#define M_PTS 16384

constexpr int BLOCK = 256;
constexpr int PPT   = 8;               // query points per thread (4x float2)
constexpr int NV    = PPT / 2;         // v2f groups
constexpr int MTILE = BLOCK * PPT;     // 2048 points per block
constexpr int NCHUNKS = 256;           // source chunks (grid.y)
constexpr int SRC_PER_CHUNK = N_SRC / NCHUNKS;  // 32
// grid = (16384/2048) x 256 = 8 x 256 = 2048 blocks = 8 blocks/CU = 32 waves/CU
// = 8 waves/SIMD (64-VGPR cap via __launch_bounds__(256, 8); ~56 live VGPRs).

typedef float v2f __attribute__((ext_vector_type(2)));

// Fused staging: each block loads its chunk's 32 sources, storing
// (-2x, -2y, -2z, r2) and w = b/(2*pi) in LDS. Inner loop per pair:
//   sq = fma(-2x,qx, fma(-2y,qy, fma(-2z,qz, q2+r2)))  -> 6 VALU + 1 rsq
// (the -2 fold removes the separate cross mul of the previous version;
// products are exact in fma, cancellation profile comparable).
// ATOMIC=false: per-chunk partials (plain stores) + reduce kernel.
// ATOMIC=true : atomicAdd fallback when ws is too small.
template <bool ATOMIC>
__global__ __launch_bounds__(BLOCK, 8) void potential_kernel(
        const float* __restrict__ b_n,
        const float* __restrict__ r_p,
        const float* __restrict__ coord,
        float*       __restrict__ outp) {
    const int t = threadIdx.x;
    const int m_base = blockIdx.x * MTILE;
    const int s_base = blockIdx.y * SRC_PER_CHUNK;

    const float CZ = 0.39894228040143267794f;     // 1/sqrt(2*pi)
    const float INV2PI = 0.15915494309189533577f; // 1/(2*pi)

    __shared__ float4 sA[SRC_PER_CHUNK];   // (-2x, -2y, -2z, r2)
    __shared__ float  sW[SRC_PER_CHUNK];   // b/(2*pi)
    if (t < SRC_PER_CHUNK) {
        int s = s_base + t;
        float x = r_p[3 * s + 0];
        float y = r_p[3 * s + 1];
        float z = r_p[3 * s + 2];
        float r2 = x * x + y * y + z * z;  // same expr as reference sum
        sA[t] = make_float4(-2.0f * x, -2.0f * y, -2.0f * z, r2);
        sW[t] = b_n[s] * INV2PI;
    }

    // element j of group h covers point p = 2*h + j
    v2f qx[NV], qy[NV], qz[NV], q2[NV], acc[NV];
#pragma unroll
    for (int h = 0; h < NV; ++h) {
#pragma unroll
        for (int j = 0; j < 2; ++j) {
            int m = m_base + (2 * h + j) * BLOCK + t;   // strided, coalesced
            float x = coord[3 * m + 0];
            float y = coord[3 * m + 1];
            float z = coord[3 * m + 2] + CZ;
            qx[h][j] = x;
            qy[h][j] = y;
            qz[h][j] = z;
            q2[h][j] = x * x + y * y + z * z;
        }
        acc[h] = (v2f){0.0f, 0.0f};
    }

    const v2f ZERO = (v2f){0.0f, 0.0f};

    __syncthreads();

#pragma unroll 4
    for (int i = 0; i < SRC_PER_CHUNK; ++i) {
        float4 sv = sA[i];                   // ds_read_b128 broadcast
        float  w  = sW[i];                   // ds_read_b32 broadcast
        v2f m2x = (v2f){sv.x, sv.x};
        v2f m2y = (v2f){sv.y, sv.y};
        v2f m2z = (v2f){sv.z, sv.z};
        v2f sr2 = (v2f){sv.w, sv.w};
        v2f wv  = (v2f){w, w};
#pragma unroll
        for (int h = 0; h < NV; ++h) {
            // sq = (q2 + r2) - 2*(r.q) via fma cascade: 3 fma + 1 add
            v2f t1 = q2[h] + sr2;
            t1 = __builtin_elementwise_fma(m2z, qz[h], t1);
            t1 = __builtin_elementwise_fma(m2y, qy[h], t1);
            v2f sq = __builtin_elementwise_fma(m2x, qx[h], t1);
            sq = __builtin_elementwise_max(sq, ZERO);   // match ref clamp
            v2f r;
            r[0] = __builtin_amdgcn_rsqf(sq[0]);   // ~1 ulp hw rsq
            r[1] = __builtin_amdgcn_rsqf(sq[1]);
            acc[h] = __builtin_elementwise_fma(wv, r, acc[h]);
        }
    }

#pragma unroll
    for (int h = 0; h < NV; ++h) {
#pragma unroll
        for (int j = 0; j < 2; ++j) {
            int m = m_base + (2 * h + j) * BLOCK + t;
            if (ATOMIC) {
                atomicAdd(&outp[m], acc[h][j]);
            } else {
                outp[(size_t)blockIdx.y * M_PTS + m] = acc[h][j];
            }
        }
    }
}

__global__ __launch_bounds__(256) void reduce_partials(
        const float* __restrict__ part, float* __restrict__ out) {
    int m = blockIdx.x * 256 + threadIdx.x;
    float s = 0.0f;
#pragma unroll 8
    for (int c = 0; c < NCHUNKS; ++c)
        s += part[(size_t)c * M_PTS + m];
    out[m] = s;
}

extern "C" void kernel_launch(void* const* d_in, const int* in_sizes, int n_in,
                              void* d_out, int out_size, void* d_ws, size_t ws_size,
                              hipStream_t stream) {
    const float* b_n   = (const float*)d_in[0];
    const float* r_p   = (const float*)d_in[1];
    const float* coord = (const float*)d_in[2];
    float* out = (float*)d_out;

    float* part = (float*)d_ws;
    const size_t need = (size_t)NCHUNKS * M_PTS * sizeof(float); // ~16.8 MB

    if (ws_size >= need) {
        // partials + reduce: no atomics, deterministic per-m order
        potential_kernel<false><<<dim3(M_PTS / MTILE, NCHUNKS), dim3(BLOCK), 0, stream>>>(
            b_n, r_p, coord, part);
        reduce_partials<<<dim3(M_PTS / 256), dim3(256), 0, stream>>>(part, out);
    } else {
        // fallback: zero out then atomic-combine
        hipMemsetAsync(d_out, 0, M_PTS * sizeof(float), stream);
        potential_kernel<true><<<dim3(M_PTS / MTILE, NCHUNKS), dim3(BLOCK), 0, stream>>>(
            b_n, r_p, coord, out);
    }
}

// Round 18
// 88.481 us; speedup vs baseline: 1.0979x; 1.0979x over previous
//
#include <hip/hip_runtime.h>

#define N_SRC 8192
#define M_PTS 16384

constexpr int BLOCK = 256;
constexpr int PPT   = 8;               // query points per thread (4x float2)
constexpr int NV    = PPT / 2;         // v2f groups
constexpr int MTILE = BLOCK * PPT;     // 2048 points per block
constexpr int NCHUNKS = 128;           // source chunks (grid.y)
constexpr int SRC_PER_CHUNK = N_SRC / NCHUNKS;  // 64
// grid = (16384/2048) x 128 = 8 x 128 = 1024 blocks = 4 blocks/CU, 16 waves/CU
// (R16 structure exactly; ONLY the inner math changed: 7 -> 6 VALU ops/pair)

typedef float v2f __attribute__((ext_vector_type(2)));

// Fused staging: each block loads its chunk's 64 sources, storing
// (-2x, -2y, -2z, r2) and w = b/(2*pi) in LDS. Inner loop per pair:
//   sq = fma(-2x,qx, fma(-2y,qy, fma(-2z,qz, q2+r2)))  -> 6 VALU + 1 rsq
// (validated round 17: absmax 0.25, passed).
// ATOMIC=false: per-chunk partials (plain stores) + reduce kernel.
// ATOMIC=true : atomicAdd fallback when ws is too small.
template <bool ATOMIC>
__global__ __launch_bounds__(BLOCK, 4) void potential_kernel(
        const float* __restrict__ b_n,
        const float* __restrict__ r_p,
        const float* __restrict__ coord,
        float*       __restrict__ outp) {
    const int t = threadIdx.x;
    const int m_base = blockIdx.x * MTILE;
    const int s_base = blockIdx.y * SRC_PER_CHUNK;

    const float CZ = 0.39894228040143267794f;     // 1/sqrt(2*pi)
    const float INV2PI = 0.15915494309189533577f; // 1/(2*pi)

    __shared__ float4 sA[SRC_PER_CHUNK];   // (-2x, -2y, -2z, r2)
    __shared__ float  sW[SRC_PER_CHUNK];   // b/(2*pi)
    if (t < SRC_PER_CHUNK) {
        int s = s_base + t;
        float x = r_p[3 * s + 0];
        float y = r_p[3 * s + 1];
        float z = r_p[3 * s + 2];
        float r2 = x * x + y * y + z * z;  // same expr as reference sum
        sA[t] = make_float4(-2.0f * x, -2.0f * y, -2.0f * z, r2);
        sW[t] = b_n[s] * INV2PI;
    }

    // element j of group h covers point p = 2*h + j
    v2f qx[NV], qy[NV], qz[NV], q2[NV], acc[NV];
#pragma unroll
    for (int h = 0; h < NV; ++h) {
#pragma unroll
        for (int j = 0; j < 2; ++j) {
            int m = m_base + (2 * h + j) * BLOCK + t;   // strided, coalesced
            float x = coord[3 * m + 0];
            float y = coord[3 * m + 1];
            float z = coord[3 * m + 2] + CZ;
            qx[h][j] = x;
            qy[h][j] = y;
            qz[h][j] = z;
            q2[h][j] = x * x + y * y + z * z;
        }
        acc[h] = (v2f){0.0f, 0.0f};
    }

    const v2f ZERO = (v2f){0.0f, 0.0f};

    __syncthreads();

#pragma unroll 4
    for (int i = 0; i < SRC_PER_CHUNK; ++i) {
        float4 sv = sA[i];                   // ds_read_b128 broadcast
        float  w  = sW[i];                   // ds_read_b32 broadcast
        v2f m2x = (v2f){sv.x, sv.x};
        v2f m2y = (v2f){sv.y, sv.y};
        v2f m2z = (v2f){sv.z, sv.z};
        v2f sr2 = (v2f){sv.w, sv.w};
        v2f wv  = (v2f){w, w};
#pragma unroll
        for (int h = 0; h < NV; ++h) {
            // sq = (q2 + r2) - 2*(r.q) via fma cascade: 3 fma + 1 add
            v2f t1 = q2[h] + sr2;
            t1 = __builtin_elementwise_fma(m2z, qz[h], t1);
            t1 = __builtin_elementwise_fma(m2y, qy[h], t1);
            v2f sq = __builtin_elementwise_fma(m2x, qx[h], t1);
            sq = __builtin_elementwise_max(sq, ZERO);   // match ref clamp
            v2f r;
            r[0] = __builtin_amdgcn_rsqf(sq[0]);   // ~1 ulp hw rsq
            r[1] = __builtin_amdgcn_rsqf(sq[1]);
            acc[h] = __builtin_elementwise_fma(wv, r, acc[h]);
        }
    }

#pragma unroll
    for (int h = 0; h < NV; ++h) {
#pragma unroll
        for (int j = 0; j < 2; ++j) {
            int m = m_base + (2 * h + j) * BLOCK + t;
            if (ATOMIC) {
                atomicAdd(&outp[m], acc[h][j]);
            } else {
                outp[(size_t)blockIdx.y * M_PTS + m] = acc[h][j];
            }
        }
    }
}

__global__ __launch_bounds__(256) void reduce_partials(
        const float* __restrict__ part, float* __restrict__ out) {
    int m = blockIdx.x * 256 + threadIdx.x;
    float s = 0.0f;
#pragma unroll 8
    for (int c = 0; c < NCHUNKS; ++c)
        s += part[(size_t)c * M_PTS + m];
    out[m] = s;
}

extern "C" void kernel_launch(void* const* d_in, const int* in_sizes, int n_in,
                              void* d_out, int out_size, void* d_ws, size_t ws_size,
                              hipStream_t stream) {
    const float* b_n   = (const float*)d_in[0];
    const float* r_p   = (const float*)d_in[1];
    const float* coord = (const float*)d_in[2];
    float* out = (float*)d_out;

    float* part = (float*)d_ws;
    const size_t need = (size_t)NCHUNKS * M_PTS * sizeof(float); // ~8.4 MB

    if (ws_size >= need) {
        // partials + reduce: no atomics, deterministic per-m order
        potential_kernel<false><<<dim3(M_PTS / MTILE, NCHUNKS), dim3(BLOCK), 0, stream>>>(
            b_n, r_p, coord, part);
        reduce_partials<<<dim3(M_PTS / 256), dim3(256), 0, stream>>>(part, out);
    } else {
        // fallback: zero out then atomic-combine
        hipMemsetAsync(d_out, 0, M_PTS * sizeof(float), stream);
        potential_kernel<true><<<dim3(M_PTS / MTILE, NCHUNKS), dim3(BLOCK), 0, stream>>>(
            b_n, r_p, coord, out);
    }
}